// Round 1
// baseline (370.509 us; speedup 1.0000x reference)
//
#include <hip/hip_runtime.h>

#define NUM_SEG 256
#define WAY 2
#define NCH 128
#define HW 65536          // 256*256
#define N_IMG 8
#define PIX_PER_BLK 2048
#define BLKS_PER_IMG (HW / PIX_PER_BLK)   // 32
#define NTHREADS 1024
#define PAD 257           // padded seg stride: bank = (c + s) % 32
#define TOTAL_SEG (N_IMG * NUM_SEG)       // 2048

__global__ __launch_bounds__(NTHREADS)
void seg_accum_kernel(const float* __restrict__ img,
                      const int* __restrict__ mask,
                      const int* __restrict__ segs,
                      float* __restrict__ out_sum,      // [TOTAL_SEG][NCH], accumulated
                      int* __restrict__ labcnt_g) {     // [TOTAL_SEG][WAY]
    __shared__ float bins[NCH * PAD];                   // ~128.5 KB
    __shared__ unsigned char segb[PIX_PER_BLK];         // 2 KB
    __shared__ int labc[NUM_SEG * WAY];                 // 2 KB

    const int bid   = blockIdx.x;
    const int n     = bid / BLKS_PER_IMG;
    const int chunk = bid % BLKS_PER_IMG;
    const int t     = threadIdx.x;

    const long pixbase = (long)n * HW + (long)chunk * PIX_PER_BLK;

    // --- zero LDS bins ---
    for (int i = t; i < NCH * PAD; i += NTHREADS) bins[i] = 0.0f;
    for (int i = t; i < NUM_SEG * WAY; i += NTHREADS) labc[i] = 0;
    __syncthreads();

    // --- stage segment ids, accumulate label counts (one pass over pixels) ---
    for (int p = t; p < PIX_PER_BLK; p += NTHREADS) {
        int s = segs[pixbase + p];
        int m = mask[pixbase + p];
        segb[p] = (unsigned char)s;
        atomicAdd(&labc[s * WAY + m], 1);
    }
    __syncthreads();

    // --- main loop: per channel, coalesced float2 loads + LDS atomic bins ---
    const float* plane0 = img + (long)n * NCH * HW + (long)chunk * PIX_PER_BLK;
    const int p0 = 2 * t;                 // this thread's 2 pixels
    const int s0 = segb[p0];
    const int s1 = segb[p0 + 1];

    #pragma unroll 1
    for (int c = 0; c < NCH; c += 4) {
        float2 v0 = *(const float2*)(plane0 + (long)(c + 0) * HW + p0);
        float2 v1 = *(const float2*)(plane0 + (long)(c + 1) * HW + p0);
        float2 v2 = *(const float2*)(plane0 + (long)(c + 2) * HW + p0);
        float2 v3 = *(const float2*)(plane0 + (long)(c + 3) * HW + p0);
        atomicAdd(&bins[(c + 0) * PAD + s0], v0.x);
        atomicAdd(&bins[(c + 0) * PAD + s1], v0.y);
        atomicAdd(&bins[(c + 1) * PAD + s0], v1.x);
        atomicAdd(&bins[(c + 1) * PAD + s1], v1.y);
        atomicAdd(&bins[(c + 2) * PAD + s0], v2.x);
        atomicAdd(&bins[(c + 2) * PAD + s1], v2.y);
        atomicAdd(&bins[(c + 3) * PAD + s0], v3.x);
        atomicAdd(&bins[(c + 3) * PAD + s1], v3.y);
    }
    __syncthreads();

    // --- flush bins to global (coalesced: i = s*128 + c matches out layout) ---
    const long outbase = (long)n * NUM_SEG * NCH;
    for (int i = t; i < NUM_SEG * NCH; i += NTHREADS) {
        int s = i >> 7;          // i / 128
        int c = i & 127;         // i % 128
        float v = bins[c * PAD + s];   // bank = (c+s)%32 -> conflict-free
        atomicAdd(&out_sum[outbase + i], v);
    }
    for (int i = t; i < NUM_SEG * WAY; i += NTHREADS) {
        atomicAdd(&labcnt_g[n * NUM_SEG * WAY + i], labc[i]);
    }
}

__global__ void finalize_kernel(float* __restrict__ out,
                                const int* __restrict__ labcnt) {
    const int nmean = TOTAL_SEG * NCH;    // 262144
    int i = blockIdx.x * blockDim.x + threadIdx.x;
    if (i < nmean) {
        int g = i >> 7;
        int c0 = labcnt[g * 2 + 0];
        int c1 = labcnt[g * 2 + 1];
        float cnt = (float)(c0 + c1);
        out[i] = out[i] / fmaxf(cnt, 1.0f);
    } else if (i < nmean + TOTAL_SEG) {
        int g = i - nmean;
        int c0 = labcnt[g * 2 + 0];
        int c1 = labcnt[g * 2 + 1];
        out[i] = (c1 > c0) ? 1.0f : 0.0f;   // argmax, ties -> 0
    }
}

extern "C" void kernel_launch(void* const* d_in, const int* in_sizes, int n_in,
                              void* d_out, int out_size, void* d_ws, size_t ws_size,
                              hipStream_t stream) {
    const float* img  = (const float*)d_in[0];   // (8,128,256,256) f32
    const int*   mask = (const int*)d_in[1];     // (8,256,256) i32 in [0,2)
    const int*   segs = (const int*)d_in[2];     // (8,256,256) i32 in [0,256)
    // d_in[3] = shot (=1), irrelevant for the flat concatenated output.

    float* out    = (float*)d_out;
    int*   labcnt = (int*)d_ws;                  // 2048*2 ints = 16 KB

    // seg_sum accumulates in-place in d_out; must be zeroed every call.
    hipMemsetAsync(out, 0, (size_t)TOTAL_SEG * NCH * sizeof(float), stream);
    hipMemsetAsync(labcnt, 0, (size_t)TOTAL_SEG * WAY * sizeof(int), stream);

    seg_accum_kernel<<<N_IMG * BLKS_PER_IMG, NTHREADS, 0, stream>>>(
        img, mask, segs, out, labcnt);

    const int totalThreads = TOTAL_SEG * NCH + TOTAL_SEG;
    finalize_kernel<<<(totalThreads + 255) / 256, 256, 0, stream>>>(out, labcnt);
}

// Round 2
// 355.235 us; speedup vs baseline: 1.0430x; 1.0430x over previous
//
#include <hip/hip_runtime.h>

#define NUM_SEG 256
#define WAY 2
#define NCH 128
#define CH_PER_BLK 64
#define HW 65536          // 256*256
#define N_IMG 8
#define PIX_PER_BLK 2048
#define CHUNKS_PER_IMG (HW / PIX_PER_BLK)   // 32
#define NTHREADS 1024
#define PAD 257           // padded seg stride: bank = (c + s) % 32
#define TOTAL_SEG (N_IMG * NUM_SEG)         // 2048
#define NBLOCKS (N_IMG * CHUNKS_PER_IMG * 2) // 512
#define PART_ELEMS (CH_PER_BLK * NUM_SEG)   // 16384 floats per block

__global__ __launch_bounds__(NTHREADS)
void seg_accum_kernel(const float* __restrict__ img,
                      const int* __restrict__ mask,
                      const int* __restrict__ segs,
                      float* __restrict__ ws_part,   // [NBLOCKS][PART_ELEMS] (use_ws)
                      float* __restrict__ out_sum,   // fallback accumulation target
                      int* __restrict__ labcnt_g,    // [TOTAL_SEG][WAY]
                      int use_ws) {
    __shared__ float bins[CH_PER_BLK * PAD];          // ~65.8 KB -> 2 blocks/CU
    __shared__ unsigned char segb[PIX_PER_BLK];       // 2 KB
    __shared__ int labc[NUM_SEG * WAY];               // 2 KB

    const int bid   = blockIdx.x;                     // n*64 + chunk*2 + h
    const int h     = bid & 1;
    const int chunk = (bid >> 1) & (CHUNKS_PER_IMG - 1);
    const int n     = bid >> 6;
    const int t     = threadIdx.x;

    const long pixbase = (long)n * HW + (long)chunk * PIX_PER_BLK;

    for (int i = t; i < CH_PER_BLK * PAD; i += NTHREADS) bins[i] = 0.0f;
    if (h == 0)
        for (int i = t; i < NUM_SEG * WAY; i += NTHREADS) labc[i] = 0;
    __syncthreads();

    // stage segment ids; half 0 also counts labels
    for (int p = t; p < PIX_PER_BLK; p += NTHREADS) {
        int s = segs[pixbase + p];
        segb[p] = (unsigned char)s;
        if (h == 0) {
            int m = mask[pixbase + p];
            atomicAdd(&labc[s * WAY + m], 1);
        }
    }
    __syncthreads();

    // main loop: 8 float2 loads in flight, then 16 LDS atomics
    const float* plane0 = img + ((long)n * NCH + h * CH_PER_BLK) * HW
                              + (long)chunk * PIX_PER_BLK;
    const int p0 = 2 * t;
    const int s0 = segb[p0];
    const int s1 = segb[p0 + 1];

    #pragma unroll 1
    for (int c = 0; c < CH_PER_BLK; c += 8) {
        float2 v[8];
        #pragma unroll
        for (int u = 0; u < 8; u++)
            v[u] = *(const float2*)(plane0 + (long)(c + u) * HW + p0);
        #pragma unroll
        for (int u = 0; u < 8; u++) {
            atomicAdd(&bins[(c + u) * PAD + s0], v[u].x);
            atomicAdd(&bins[(c + u) * PAD + s1], v[u].y);
        }
    }
    __syncthreads();

    // flush: disjoint workspace region per block (coalesced) or atomic fallback
    if (use_ws) {
        float* dst = ws_part + (long)bid * PART_ELEMS;
        for (int i = t; i < PART_ELEMS; i += NTHREADS) {
            int c = i & (CH_PER_BLK - 1);
            int s = i >> 6;
            dst[i] = bins[c * PAD + s];     // bank (c+s)%32: conflict-free
        }
    } else {
        const long outbase = (long)n * NUM_SEG * NCH + h * CH_PER_BLK;
        for (int i = t; i < PART_ELEMS; i += NTHREADS) {
            int c = i & (CH_PER_BLK - 1);
            int s = i >> 6;
            atomicAdd(&out_sum[outbase + (long)s * NCH + c], bins[c * PAD + s]);
        }
    }
    if (h == 0)
        for (int i = t; i < NUM_SEG * WAY; i += NTHREADS)
            atomicAdd(&labcnt_g[n * NUM_SEG * WAY + i], labc[i]);
}

// reduce 32 chunk-partials + finalize (divide by count, emit labels)
__global__ void reduce_ws_kernel(const float* __restrict__ ws_part,
                                 const int* __restrict__ labcnt,
                                 float* __restrict__ out) {
    const int nmean = TOTAL_SEG * NCH;    // 262144
    int i = blockIdx.x * blockDim.x + threadIdx.x;
    if (i < nmean) {
        int c  = i & (NCH - 1);
        int g  = i >> 7;                  // n*256 + s
        int s  = g & (NUM_SEG - 1);
        int n  = g >> 8;
        int hh = c >> 6;
        int cl = c & (CH_PER_BLK - 1);
        const float* base = ws_part + ((long)n * 64 + hh) * PART_ELEMS
                                    + s * CH_PER_BLK + cl;
        float acc = 0.0f;
        #pragma unroll
        for (int chunk = 0; chunk < CHUNKS_PER_IMG; chunk++)
            acc += base[(long)chunk * 2 * PART_ELEMS];
        int c0 = labcnt[g * 2 + 0];
        int c1 = labcnt[g * 2 + 1];
        out[i] = acc / fmaxf((float)(c0 + c1), 1.0f);
    } else if (i < nmean + TOTAL_SEG) {
        int g = i - nmean;
        out[i] = (labcnt[g * 2 + 1] > labcnt[g * 2 + 0]) ? 1.0f : 0.0f;
    }
}

// fallback finalize when out_sum was accumulated by atomics
__global__ void finalize_kernel(float* __restrict__ out,
                                const int* __restrict__ labcnt) {
    const int nmean = TOTAL_SEG * NCH;
    int i = blockIdx.x * blockDim.x + threadIdx.x;
    if (i < nmean) {
        int g = i >> 7;
        float cnt = (float)(labcnt[g * 2 + 0] + labcnt[g * 2 + 1]);
        out[i] = out[i] / fmaxf(cnt, 1.0f);
    } else if (i < nmean + TOTAL_SEG) {
        int g = i - nmean;
        out[i] = (labcnt[g * 2 + 1] > labcnt[g * 2 + 0]) ? 1.0f : 0.0f;
    }
}

extern "C" void kernel_launch(void* const* d_in, const int* in_sizes, int n_in,
                              void* d_out, int out_size, void* d_ws, size_t ws_size,
                              hipStream_t stream) {
    const float* img  = (const float*)d_in[0];
    const int*   mask = (const int*)d_in[1];
    const int*   segs = (const int*)d_in[2];

    float* out = (float*)d_out;

    const size_t part_bytes = (size_t)NBLOCKS * PART_ELEMS * sizeof(float); // 33.5 MB
    const size_t lab_bytes  = (size_t)TOTAL_SEG * WAY * sizeof(int);        // 16 KB
    const int use_ws = (ws_size >= part_bytes + lab_bytes) ? 1 : 0;

    float* ws_part = (float*)d_ws;
    int*   labcnt  = (int*)((char*)d_ws + (use_ws ? part_bytes : 0));

    hipMemsetAsync(labcnt, 0, lab_bytes, stream);
    if (!use_ws)
        hipMemsetAsync(out, 0, (size_t)TOTAL_SEG * NCH * sizeof(float), stream);

    seg_accum_kernel<<<NBLOCKS, NTHREADS, 0, stream>>>(
        img, mask, segs, ws_part, out, labcnt, use_ws);

    const int totalThreads = TOTAL_SEG * NCH + TOTAL_SEG;
    if (use_ws)
        reduce_ws_kernel<<<(totalThreads + 255) / 256, 256, 0, stream>>>(
            ws_part, labcnt, out);
    else
        finalize_kernel<<<(totalThreads + 255) / 256, 256, 0, stream>>>(out, labcnt);
}

// Round 3
// 144.341 us; speedup vs baseline: 2.5669x; 2.4611x over previous
//
#include <hip/hip_runtime.h>

#define NUM_SEG 256
#define WAY 2
#define NCH 128
#define HW 65536                     // 256*256
#define N_IMG 8
#define PIX_PER_BLK 2048
#define CHUNKS_PER_IMG 32            // 65536/2048
#define NTHREADS 1024
#define TOTAL_SEG (N_IMG * NUM_SEG)  // 2048
#define NBLOCKS (N_IMG * CHUNKS_PER_IMG)   // 256
#define PART_ELEMS (NUM_SEG * NCH)   // 32768 floats per block partial
#define KCHUNKS (PIX_PER_BLK / 32)   // 64

typedef __attribute__((ext_vector_type(8))) short short8;
typedef __attribute__((ext_vector_type(4))) float f32x4;

static __device__ __forceinline__ unsigned short f2bf(float f) {
    // round-to-nearest-even f32 -> bf16
    unsigned int u = __float_as_uint(f);
    unsigned int r = u + 0x7FFFu + ((u >> 16) & 1u);
    return (unsigned short)(r >> 16);
}

static __device__ __forceinline__ short8 cvt8(float4 lo, float4 hi) {
    short8 r;
    r[0] = (short)f2bf(lo.x); r[1] = (short)f2bf(lo.y);
    r[2] = (short)f2bf(lo.z); r[3] = (short)f2bf(lo.w);
    r[4] = (short)f2bf(hi.x); r[5] = (short)f2bf(hi.y);
    r[6] = (short)f2bf(hi.z); r[7] = (short)f2bf(hi.w);
    return r;
}

// One-hot MFMA segment-sum: C[ch][seg] += F[ch][k] * (seg(k)==seg)
__global__ __launch_bounds__(NTHREADS, 4)
void seg_mfma_kernel(const float* __restrict__ img,
                     const int* __restrict__ mask,
                     const int* __restrict__ segs,
                     float* __restrict__ ws_part,      // [NBLOCKS][PART_ELEMS]
                     int* __restrict__ labcnt_g) {     // [TOTAL_SEG][WAY]
    // one-hot B tiles, double buffered: [buf][seg][k] bf16 (32 KB).
    // Reused as fp32 strip scratch (8 KB) in the epilogue.
    __shared__ __align__(16) unsigned short OH[2][NUM_SEG][32];
    __shared__ unsigned char segb[PIX_PER_BLK];       // 2 KB
    __shared__ int labc[NUM_SEG * WAY];               // 2 KB

    const int bid   = blockIdx.x;        // n*32 + chunk
    const int n     = bid >> 5;
    const int chunk = bid & 31;
    const int t     = threadIdx.x;
    const int lane  = t & 63;
    const int w     = t >> 6;            // wave 0..15
    const int mg    = w & 3;             // channel group: ch base 32*mg
    const int ng    = w >> 2;            // seg group:     seg base 64*ng

    const long pixbase = (long)n * HW + chunk * PIX_PER_BLK;

    // --- zero OH (8192 dwords) and labc ---
    {
        int4* p = (int4*)&OH[0][0][0];
        int4 z; z.x = z.y = z.z = z.w = 0;
        p[t] = z;
        p[t + NTHREADS] = z;
    }
    for (int i = t; i < NUM_SEG * WAY; i += NTHREADS) labc[i] = 0;
    __syncthreads();

    // --- stage seg ids (u8) + label histogram ---
    for (int p = t; p < PIX_PER_BLK; p += NTHREADS) {
        int s = segs[pixbase + p];
        segb[p] = (unsigned char)s;
        atomicAdd(&labc[s * 2 + mask[pixbase + p]], 1);
    }
    __syncthreads();

    // --- A-operand addressing: lane holds F[c][k..k+7] (8 contiguous px) ---
    // A-frag layout (16x16x32): row = lane&15, k = 8*(lane>>4)+j
    const int cA0 = 32 * mg + (lane & 15);
    const int kA  = 8 * (lane >> 4);
    const float* gA0 = img + (long)(n * NCH + cA0     ) * HW + chunk * PIX_PER_BLK + kA;
    const float* gA1 = img + (long)(n * NCH + cA0 + 16) * HW + chunk * PIX_PER_BLK + kA;

    // wave0 one-hot bookkeeping (lane = k within chunk)
    const bool sc = (t < 32);
    int s_prev = 0, s_cur = 0, s_next = 0;
    if (sc) {
        s_cur = segb[t];
        OH[0][s_cur][t] = 0x3F80;        // bf16 1.0
    }

    // prefetch A for chunk 0
    float4 a0l = *(const float4*)(gA0);
    float4 a0h = *(const float4*)(gA0 + 4);
    float4 a1l = *(const float4*)(gA1);
    float4 a1h = *(const float4*)(gA1 + 4);

    f32x4 acc[2][4] = {};
    __syncthreads();    // OH[0] scatter + zeros visible

    for (int j = 0; j < KCHUNKS; ++j) {
        const int cur = j & 1, nxt = cur ^ 1;

        // convert prefetched A regs -> bf16 frags
        short8 a0 = cvt8(a0l, a0h);
        short8 a1 = cvt8(a1l, a1h);

        // issue prefetch for chunk j+1 (hides HBM/L2 latency under MFMA)
        if (j + 1 < KCHUNKS) {
            const float* p0 = gA0 + (j + 1) * 32;
            const float* p1 = gA1 + (j + 1) * 32;
            a0l = *(const float4*)(p0);
            a0h = *(const float4*)(p0 + 4);
            a1l = *(const float4*)(p1);
            a1h = *(const float4*)(p1 + 4);
            if (sc) s_next = segb[(j + 1) * 32 + t];
        }

        // B frags from OH[cur] + 8 MFMAs
        // B layout: col = lane&15 (seg), k = 8*(lane>>4)+j  -> contiguous b128
        #pragma unroll
        for (int nj = 0; nj < 4; ++nj) {
            const unsigned short* bp = &OH[cur][64 * ng + 16 * nj + (lane & 15)][kA];
            short8 b = *(const short8*)bp;
            acc[0][nj] = __builtin_amdgcn_mfma_f32_16x16x32_bf16(a0, b, acc[0][nj], 0, 0, 0);
            acc[1][nj] = __builtin_amdgcn_mfma_f32_16x16x32_bf16(a1, b, acc[1][nj], 0, 0, 0);
        }

        // wave0: clear chunk j-1 ones in OH[nxt], scatter chunk j+1
        if (sc) {
            if (j >= 1)           OH[nxt][s_prev][t] = 0;
            if (j + 1 < KCHUNKS)  OH[nxt][s_next][t] = 0x3F80;
            s_prev = s_cur;
            s_cur  = s_next;
        }
        __syncthreads();
    }

    // --- epilogue: transpose acc -> [seg][ch] partials via 8 KB LDS strip ---
    float* strip = (float*)&OH[0][0][0];              // [16 segs][128 ch] fp32
    float* wsb = ws_part + (long)bid * PART_ELEMS;
    for (int nt = 0; nt < 16; ++nt) {
        if (ng == (nt >> 2)) {
            const int nj = nt & 3;
            // D layout: col(seg-local) = lane&15, row(ch-local) = 4*(lane>>4)+r
            #pragma unroll
            for (int m = 0; m < 2; ++m)
                #pragma unroll
                for (int r = 0; r < 4; ++r)
                    strip[(lane & 15) * NCH + 32 * mg + 16 * m + 4 * (lane >> 4) + r] =
                        acc[m][nj][r];
        }
        __syncthreads();
        {   // flush 2048 floats, coalesced
            float2 v = ((const float2*)strip)[t];
            ((float2*)(wsb + nt * 2048))[t] = v;
        }
        __syncthreads();
    }

    // --- label count flush ---
    for (int i = t; i < NUM_SEG * WAY; i += NTHREADS)
        atomicAdd(&labcnt_g[n * NUM_SEG * WAY + i], labc[i]);
}

// sum 32 chunk-partials, divide by count, emit labels
__global__ void reduce_ws_kernel(const float* __restrict__ ws_part,
                                 const int* __restrict__ labcnt,
                                 float* __restrict__ out) {
    const int nmean = TOTAL_SEG * NCH;    // 262144
    int i = blockIdx.x * blockDim.x + threadIdx.x;
    if (i < nmean) {
        int nimg = i >> 15;               // / 32768
        int rem  = i & 32767;             // s*128 + c
        const float* base = ws_part + (long)nimg * 32 * PART_ELEMS + rem;
        float acc = 0.0f;
        #pragma unroll
        for (int j = 0; j < CHUNKS_PER_IMG; ++j)
            acc += base[(long)j * PART_ELEMS];
        int g  = i >> 7;                  // n*256 + s
        int c0 = labcnt[g * 2 + 0];
        int c1 = labcnt[g * 2 + 1];
        out[i] = acc / fmaxf((float)(c0 + c1), 1.0f);
    } else if (i < nmean + TOTAL_SEG) {
        int g = i - nmean;
        out[i] = (labcnt[g * 2 + 1] > labcnt[g * 2 + 0]) ? 1.0f : 0.0f;
    }
}

extern "C" void kernel_launch(void* const* d_in, const int* in_sizes, int n_in,
                              void* d_out, int out_size, void* d_ws, size_t ws_size,
                              hipStream_t stream) {
    const float* img  = (const float*)d_in[0];   // (8,128,256,256) f32
    const int*   mask = (const int*)d_in[1];     // (8,256,256) i32 in [0,2)
    const int*   segs = (const int*)d_in[2];     // (8,256,256) i32 in [0,256)

    float* out = (float*)d_out;

    const size_t part_bytes = (size_t)NBLOCKS * PART_ELEMS * sizeof(float); // 32 MB
    float* ws_part = (float*)d_ws;
    int*   labcnt  = (int*)((char*)d_ws + part_bytes);

    hipMemsetAsync(labcnt, 0, (size_t)TOTAL_SEG * WAY * sizeof(int), stream);

    seg_mfma_kernel<<<NBLOCKS, NTHREADS, 0, stream>>>(
        img, mask, segs, ws_part, labcnt);

    const int totalThreads = TOTAL_SEG * NCH + TOTAL_SEG;   // 264192
    reduce_ws_kernel<<<(totalThreads + 255) / 256, 256, 0, stream>>>(
        ws_part, labcnt, out);
}

// Round 5
// 87.942 us; speedup vs baseline: 4.2131x; 1.6413x over previous
//
#include <hip/hip_runtime.h>

#define NUM_SEG 256
#define WAY 2
#define NCH 128
#define HW 65536                     // 256*256
#define N_IMG 8
#define PIX_PER_BLK 2048
#define CHUNKS_PER_IMG 32
#define NTHREADS 1024
#define TOTAL_SEG (N_IMG * NUM_SEG)  // 2048
#define NBLOCKS (N_IMG * CHUNKS_PER_IMG)   // 256
#define PART_ELEMS (NUM_SEG * NCH)   // 32768
#define KW 32                        // pixels per K-chunk
#define NITER (PIX_PER_BLK / KW)     // 64
#define LDR 40                       // padded row, shorts (80 B, 16B-aligned)

typedef __attribute__((ext_vector_type(8))) short short8;
typedef __attribute__((ext_vector_type(4))) short short4v;
typedef __attribute__((ext_vector_type(4))) float f32x4;

static __device__ __forceinline__ unsigned short f2bf(float f) {
    unsigned int u = __float_as_uint(f);
    unsigned int r = u + 0x7FFFu + ((u >> 16) & 1u);
    return (unsigned short)(r >> 16);
}

static __device__ __forceinline__ short4v cvt4(float4 v) {
    short4v r;
    r[0] = (short)f2bf(v.x); r[1] = (short)f2bf(v.y);
    r[2] = (short)f2bf(v.z); r[3] = (short)f2bf(v.w);
    return r;
}

// One-hot MFMA segment-sum, round-3 control flow + dbuf LDS-staged A.
// C[ch][seg] += F[ch][k] * (seg(k)==seg)
__global__ __launch_bounds__(NTHREADS, 8)
void seg_mfma_kernel(const float* __restrict__ img,
                     const int* __restrict__ mask,
                     const int* __restrict__ segs,
                     float* __restrict__ ws_part,      // [NBLOCKS][PART_ELEMS]
                     int* __restrict__ labcnt_g) {     // [TOTAL_SEG][WAY]
    __shared__ __align__(16) unsigned short OH[2][NUM_SEG][LDR]; // 40 KB one-hot B
    __shared__ __align__(16) unsigned short At[2][NCH][LDR];     // 20 KB bf16 A
    __shared__ unsigned char segb[PIX_PER_BLK];                  // 2 KB
    __shared__ int labc[NUM_SEG * WAY];                          // 2 KB
    // total exactly 64 KB -> 2 blocks/CU

    const int bid   = blockIdx.x;        // n*32 + chunk
    const int n     = bid >> 5;
    const int chunk = bid & 31;
    const int t     = threadIdx.x;
    const int lane  = t & 63;
    const int w     = t >> 6;            // wave 0..15
    const int mg    = w & 3;             // ch group base 32*mg
    const int ng    = w >> 2;            // seg group base 64*ng

    const long pixbase = (long)n * HW + chunk * PIX_PER_BLK;

    // zero OH (both buffers incl. pads) + labc
    {
        int4 z; z.x = z.y = z.z = z.w = 0;
        int4* p = (int4*)&OH[0][0][0];
        for (int i = t; i < (2 * NUM_SEG * LDR * 2) / 16; i += NTHREADS) p[i] = z;
        for (int i = t; i < NUM_SEG * WAY; i += NTHREADS) labc[i] = 0;
    }
    __syncthreads();

    // stage seg ids (u8) + label histogram
    for (int p = t; p < PIX_PER_BLK; p += NTHREADS) {
        int s = segs[pixbase + p];
        segb[p] = (unsigned char)s;
        atomicAdd(&labc[s * 2 + mask[pixbase + p]], 1);
    }

    // A staging addressing: 8 threads/row, float4 each (32 px/chunk)
    const int arow = t >> 3;             // 0..127
    const int acol = (t & 7) * 4;        // 0..28
    const float* gA = img + (long)(n * NCH + arow) * HW
                          + chunk * PIX_PER_BLK + acol;

    // load chunk 0
    float4 fc = *(const float4*)(gA);
    __syncthreads();                      // segb + OH zeros visible

    // build chunk 0 into At[0], OH[0]
    *(short4v*)&At[0][arow][acol] = cvt4(fc);
    const bool sc = (t < KW);             // wave-0 lanes 0..31 own one-hot cols
    int s_prev = -1, s_cur = -1;
    if (sc) {
        s_cur = segb[t];
        OH[0][s_cur][t] = 0x3F80;         // bf16 1.0
    }
    fc = *(const float4*)(gA + KW);       // issue load chunk 1
    __syncthreads();                      // At[0], OH[0] visible

    f32x4 acc[2][4] = {};
    const int l15 = lane & 15;
    const int kA  = 8 * (lane >> 4);

    for (int it = 0; it < NITER; ++it) {
        const int cur = it & 1, nxt = cur ^ 1;

        // issue load for chunk it+2 (consumed next iteration)
        float4 fn = fc;
        if (it + 2 < NITER) fn = *(const float4*)(gA + (it + 2) * KW);
        int s_next = 0;
        if (sc && it + 1 < NITER) s_next = segb[(it + 1) * KW + t];

        // MFMA on chunk it (reads cur buffers only)
        short8 a0 = *(const short8*)&At[cur][32 * mg      + l15][kA];
        short8 a1 = *(const short8*)&At[cur][32 * mg + 16 + l15][kA];
        #pragma unroll
        for (int nj = 0; nj < 4; ++nj) {
            short8 b = *(const short8*)&OH[cur][64 * ng + 16 * nj + l15][kA];
            acc[0][nj] = __builtin_amdgcn_mfma_f32_16x16x32_bf16(a0, b, acc[0][nj], 0, 0, 0);
            acc[1][nj] = __builtin_amdgcn_mfma_f32_16x16x32_bf16(a1, b, acc[1][nj], 0, 0, 0);
        }

        // stage chunk it+1 into nxt buffers (disjoint from cur)
        if (it + 1 < NITER) {
            *(short4v*)&At[nxt][arow][acol] = cvt4(fc);   // fc loaded last iter
            if (sc) {
                // nxt one-hot buffer holds chunk it-1's entries: clear, then set
                if (s_prev >= 0 && s_prev != s_next) OH[nxt][s_prev][t] = 0;
                OH[nxt][s_next][t] = 0x3F80;
                s_prev = s_cur;
                s_cur  = s_next;
            }
        }
        __syncthreads();
        fc = fn;
    }

    // epilogue: transpose acc -> [seg][ch] partials via LDS strip (reuse OH)
    float* strip = (float*)&OH[0][0][0];              // [16 segs][128 ch] fp32
    float* wsb = ws_part + (long)bid * PART_ELEMS;
    for (int nt = 0; nt < 16; ++nt) {
        if (ng == (nt >> 2)) {
            const int nj = nt & 3;
            // D layout: col(seg-local)=lane&15, row(ch-local)=4*(lane>>4)+r
            #pragma unroll
            for (int m = 0; m < 2; ++m)
                #pragma unroll
                for (int r = 0; r < 4; ++r)
                    strip[l15 * NCH + 32 * mg + 16 * m + 4 * (lane >> 4) + r] =
                        acc[m][nj][r];
        }
        __syncthreads();
        {
            float2 v = ((const float2*)strip)[t];
            ((float2*)(wsb + nt * 2048))[t] = v;
        }
        __syncthreads();
    }

    for (int i = t; i < NUM_SEG * WAY; i += NTHREADS)
        atomicAdd(&labcnt_g[n * NUM_SEG * WAY + i], labc[i]);
}

// sum 32 chunk-partials, divide by count, emit labels
__global__ void reduce_ws_kernel(const float* __restrict__ ws_part,
                                 const int* __restrict__ labcnt,
                                 float* __restrict__ out) {
    const int nmean = TOTAL_SEG * NCH;    // 262144
    int i = blockIdx.x * blockDim.x + threadIdx.x;
    if (i < nmean) {
        int nimg = i >> 15;               // / 32768
        int rem  = i & 32767;             // s*128 + c
        const float* base = ws_part + (long)nimg * 32 * PART_ELEMS + rem;
        float acc = 0.0f;
        #pragma unroll
        for (int j = 0; j < CHUNKS_PER_IMG; ++j)
            acc += base[(long)j * PART_ELEMS];
        int g  = i >> 7;                  // n*256 + s
        int c0 = labcnt[g * 2 + 0];
        int c1 = labcnt[g * 2 + 1];
        out[i] = acc / fmaxf((float)(c0 + c1), 1.0f);
    } else if (i < nmean + TOTAL_SEG) {
        int g = i - nmean;
        out[i] = (labcnt[g * 2 + 1] > labcnt[g * 2 + 0]) ? 1.0f : 0.0f;
    }
}

extern "C" void kernel_launch(void* const* d_in, const int* in_sizes, int n_in,
                              void* d_out, int out_size, void* d_ws, size_t ws_size,
                              hipStream_t stream) {
    const float* img  = (const float*)d_in[0];   // (8,128,256,256) f32
    const int*   mask = (const int*)d_in[1];     // (8,256,256) i32 in [0,2)
    const int*   segs = (const int*)d_in[2];     // (8,256,256) i32 in [0,256)

    float* out = (float*)d_out;

    const size_t part_bytes = (size_t)NBLOCKS * PART_ELEMS * sizeof(float); // 32 MB
    float* ws_part = (float*)d_ws;
    int*   labcnt  = (int*)((char*)d_ws + part_bytes);

    hipMemsetAsync(labcnt, 0, (size_t)TOTAL_SEG * WAY * sizeof(int), stream);

    seg_mfma_kernel<<<NBLOCKS, NTHREADS, 0, stream>>>(
        img, mask, segs, ws_part, labcnt);

    const int totalThreads = TOTAL_SEG * NCH + TOTAL_SEG;   // 264192
    reduce_ws_kernel<<<(totalThreads + 255) / 256, 256, 0, stream>>>(
        ws_part, labcnt, out);
}